// Round 3
// baseline (249.623 us; speedup 1.0000x reference)
//
#include <hip/hip_runtime.h>

// crossCorrelation3D: local (9x9x9) NCC loss, fused single kernel.
// B=2, C=1, D=H=W=160, fp32. Output = -mean(cc), scalar.
//
// R3 structure: block = 16x16 (h,w) tile, marches DCHUNK=20 depths
// (grid 10x10x16 = 1600 blocks ~ 6.25/CU; R2's 1000 blocks was grid-limited
// at 41% occupancy). Per plane: halo 24x24 of (I, T=(raw+1)/2) is prefetched
// into REGISTERS one plane ahead (hides ~900cyc HBM latency), stored to LDS,
// then separable box sums: w 9-taps -> tmp5, h 9-taps (all 256 threads,
// 5 outputs each) -> Pbuf. D-window = per-thread register ring of 9 planes
// x 5 fields with running sums (statically indexed: inner loop unrolled by 9,
// outer base is a multiple of 9). flow is prefetched one plane ahead too.
// Epilogue: wave shuffle reduce -> double atomicAdd; last block (atomic
// counter) writes -mean directly (no finalize kernel).

constexpr int NB = 2, ND = 160, NH = 160, NW = 160;
constexpr int TH = 16, TW = 16;
constexpr int DCHUNK = 20;
constexpr int NDCH = ND / DCHUNK;          // 8
constexpr int NPLANES = DCHUNK + 8;        // 28
constexpr int NBLOCKS = (NW / TW) * (NH / TH) * NB * NDCH;  // 1600
constexpr float INV_K = 1.0f / 729.0f;
constexpr double INV_COUNT = 1.0 / (double(NB) * ND * NH * NW);
constexpr long PLSTRIDE = (long)NH * NW;   // 25600

__global__ void __launch_bounds__(256)
cc3d_main(const float* __restrict__ in, const float* __restrict__ tg,
          const float* __restrict__ fl, float* __restrict__ out,
          double* __restrict__ acc_ws, unsigned* __restrict__ cnt_ws)
{
    __shared__ float inT[24 * 24];
    __shared__ float tgT[24 * 24];
    __shared__ float tmp5[5 * 24 * 16];
    __shared__ float Pbuf[5 * 16 * 16];
    __shared__ float red[4];

    const int tid = threadIdx.x;
    const int w0 = blockIdx.x * TW;
    const int h0 = blockIdx.y * TH;
    const int bz = blockIdx.z;
    const int b  = bz / NDCH;
    const int d0 = (bz - b * NDCH) * DCHUNK;

    // ---- halo-load metadata (tid<144: row r, 4-wide segment q) ----
    const int hr = tid / 6, hq = tid - hr * 6;
    const int gh = h0 - 4 + hr;
    const int gw = w0 - 4 + hq * 4;   // segment entirely in or out of bounds
    const bool ld_active = (tid < 144) &&
        ((unsigned)gh < (unsigned)NH) && ((unsigned)gw < (unsigned)NW);
    const long haloBase = (long)b * ND * PLSTRIDE + (long)gh * NW + gw;

    // ---- consume metadata ----
    const int hh = tid >> 4, ww = tid & 15;
    const long flBase = (long)b * ND * PLSTRIDE + (long)(h0 + hh) * NW + (w0 + ww);

    float4 pvi = make_float4(0.f, 0.f, 0.f, 0.f);
    float4 pvt = make_float4(0.f, 0.f, 0.f, 0.f);
    float flow_pre = 0.f;

    float ring[45];
    #pragma unroll
    for (int i = 0; i < 45; ++i) ring[i] = 0.f;
    float S[5] = {0.f, 0.f, 0.f, 0.f, 0.f};
    float acc = 0.f;

    // ---- prologue: issue halo loads for plane 0 (dp = d0-4) ----
    {
        int dp = d0 - 4;
        if (ld_active && dp >= 0) {
            const float* pi = in + haloBase + (long)dp * PLSTRIDE;
            const float* pt = tg + haloBase + (long)dp * PLSTRIDE;
            pvi = *reinterpret_cast<const float4*>(pi);
            pvt = *reinterpret_cast<const float4*>(pt);
        }
    }

    for (int pbase = 0; pbase < NPLANES; pbase += 9) {
        #pragma unroll
        for (int jj = 0; jj < 9; ++jj) {
            const int p = pbase + jj;       // p % 9 == jj (pbase multiple of 9)
            if (p < NPLANES) {              // block-uniform
                const int dp = d0 - 4 + p;
                const bool vald = (dp >= 0) && (dp < ND);  // block-uniform

                // grab flow value issued last iteration BEFORE re-issue
                const float flow_cur = flow_pre;

                // ---- store prefetched halo plane p to LDS ----
                if (vald && tid < 144) {
                    float4 wi, wt;
                    if (ld_active) {
                        wi = pvi;
                        wt.x = fmaf(pvt.x, 0.5f, 0.5f);
                        wt.y = fmaf(pvt.y, 0.5f, 0.5f);
                        wt.z = fmaf(pvt.z, 0.5f, 0.5f);
                        wt.w = fmaf(pvt.w, 0.5f, 0.5f);
                    } else {
                        wi = make_float4(0.f, 0.f, 0.f, 0.f);
                        wt = make_float4(0.f, 0.f, 0.f, 0.f);
                    }
                    reinterpret_cast<float4*>(inT)[tid] = wi;
                    reinterpret_cast<float4*>(tgT)[tid] = wt;
                }

                // ---- issue loads for plane p+1 (and next flow) ----
                if (p + 1 < NPLANES) {
                    const int dpn = dp + 1;
                    if (ld_active && dpn >= 0 && dpn < ND) {
                        const float* pi = in + haloBase + (long)dpn * PLSTRIDE;
                        const float* pt = tg + haloBase + (long)dpn * PLSTRIDE;
                        pvi = *reinterpret_cast<const float4*>(pi);
                        pvt = *reinterpret_cast<const float4*>(pt);
                    }
                    if (p >= 7) {   // flow for output consumed at iter p+1
                        flow_pre = fl[flBase + (long)(d0 + p - 7) * PLSTRIDE];
                    }
                }

                if (vald) {
                    __syncthreads();   // A: halo ready (also: Pbuf consume done)
                    // ---- step2: w-direction 9-sums -> tmp5[5][24][16] ----
                    #pragma unroll
                    for (int rep = 0; rep < 2; ++rep) {
                        const int idx = tid + rep * 256;
                        if (idx < 384) {
                            const int rr = idx >> 4, wo = idx & 15;
                            const float* ir = inT + rr * 24 + wo;
                            const float* tr = tgT + rr * 24 + wo;
                            float s0 = 0.f, s1 = 0.f, s2 = 0.f, s3 = 0.f, s4 = 0.f;
                            #pragma unroll
                            for (int k = 0; k < 9; ++k) {
                                const float iv = ir[k];
                                const float t  = tr[k];   // pad cells already 0
                                s0 += t;
                                s1 += iv;
                                s2 = fmaf(t,  t,  s2);
                                s3 = fmaf(iv, iv, s3);
                                s4 = fmaf(iv, t,  s4);
                            }
                            const int o = rr * 16 + wo;
                            tmp5[o]          = s0;
                            tmp5[384 + o]    = s1;
                            tmp5[768 + o]    = s2;
                            tmp5[1152 + o]   = s3;
                            tmp5[1536 + o]   = s4;
                        }
                    }
                    __syncthreads();   // B: tmp5 ready; halo free for next write
                    // ---- step3: h-direction 9-taps, ALL 256 threads ----
                    #pragma unroll
                    for (int f = 0; f < 5; ++f) {
                        const float* bp = tmp5 + f * 384 + hh * 16 + ww;
                        float s = 0.f;
                        #pragma unroll
                        for (int r9 = 0; r9 < 9; ++r9) s += bp[r9 * 16];
                        Pbuf[f * 256 + tid] = s;
                    }
                    __syncthreads();   // C: Pbuf ready
                }

                // ---- D-window ring update (slot jj, static) ----
                #pragma unroll
                for (int f = 0; f < 5; ++f) {
                    const float pn = vald ? Pbuf[f * 256 + tid] : 0.f;
                    S[f] += pn - ring[jj * 5 + f];
                    ring[jj * 5 + f] = pn;
                }

                // ---- consume: output dout = d0 + p - 8 ----
                if (p >= 8) {
                    const float wgt = 1.0f / (1.0f + __expf(-flow_cur));
                    const float Ts = S[0], Is = S[1], TTs = S[2], IIs = S[3], ITs = S[4];
                    const float Ihat = Is * INV_K;
                    const float That = Ts * INV_K;
                    const float cross = ITs - Ihat * Ts - That * Is + That * Ihat * 729.0f;
                    const float T_var = TTs - 2.0f * That * Ts + That * That * 729.0f;
                    const float I_var = IIs - 2.0f * Ihat * Is + Ihat * Ihat * 729.0f;
                    acc += cross * cross * wgt / (T_var * I_var + 1e-5f);
                }
            }
        }
    }

    // ---- block reduction -> device atomic; last block finalizes ----
    #pragma unroll
    for (int off = 32; off > 0; off >>= 1) acc += __shfl_down(acc, off);
    if ((tid & 63) == 0) red[tid >> 6] = acc;
    __syncthreads();
    if (tid == 0) {
        const double v = (double)red[0] + (double)red[1] + (double)red[2] + (double)red[3];
        atomicAdd(acc_ws, v);
        __threadfence();
        const unsigned done = atomicAdd(cnt_ws, 1u);
        if (done == (unsigned)(NBLOCKS - 1)) {
            __threadfence();
            const double a = atomicAdd(acc_ws, 0.0);   // coherent read (bypass L1)
            out[0] = (float)(-(a * INV_COUNT));
        }
    }
}

extern "C" void kernel_launch(void* const* d_in, const int* in_sizes, int n_in,
                              void* d_out, int out_size, void* d_ws, size_t ws_size,
                              hipStream_t stream)
{
    const float* in = (const float*)d_in[0];   // 'input'
    const float* tg = (const float*)d_in[1];   // 'target'
    const float* fl = (const float*)d_in[2];   // 'flow'
    float* out = (float*)d_out;
    double* acc = (double*)d_ws;
    unsigned* cnt = (unsigned*)((char*)d_ws + 8);

    hipMemsetAsync(d_ws, 0, 16, stream);  // zero acc + counter (graph-safe)

    dim3 grid(NW / TW, NH / TH, NB * NDCH);  // (10, 10, 16) = 1600 blocks
    cc3d_main<<<grid, dim3(256), 0, stream>>>(in, tg, fl, out, acc, cnt);
}

// Round 4
// 244.170 us; speedup vs baseline: 1.0223x; 1.0223x over previous
//
#include <hip/hip_runtime.h>

// crossCorrelation3D: local (9x9x9) NCC loss, fused single kernel.
// B=2, C=1, D=H=W=160, fp32. Output = -mean(cc), scalar.
//
// R4: block = 16x16 (h,w) tile marching DCHUNK=20 depths (1600 blocks).
// Per plane: halo 24x24 of (I, T=(raw+1)/2) prefetched into registers ONE
// plane ahead, stored into DOUBLE-BUFFERED LDS halos (kills barrier A ->
// 2 barriers/plane). Separable box sums: step2 w-direction 9-taps (384
// positions over 256 threads) -> tmp5 (field stride 392 = 384+8 pad so
// step3's same-(r,w)-different-f lanes land on different banks: 4-way ->
// 2-way = free). step3: 80-thread h-direction SLIDING sums (the reuse R3
// wrongly discarded) -> Pbuf. D-window: per-thread register ring of 9
// planes x 5 fields, statically indexed (inner loop unrolled by 9).
// Boundary planes run uniformly on zeroed halos (no divergent barriers).
// flow prefetched one plane ahead. Fused finalize via atomic counter.

constexpr int NB = 2, ND = 160, NH = 160, NW = 160;
constexpr int TH = 16, TW = 16;
constexpr int DCHUNK = 20;
constexpr int NDCH = ND / DCHUNK;          // 8
constexpr int NPLANES = DCHUNK + 8;        // 28
constexpr int NBLOCKS = (NW / TW) * (NH / TH) * NB * NDCH;  // 1600
constexpr float INV_K = 1.0f / 729.0f;
constexpr double INV_COUNT = 1.0 / (double(NB) * ND * NH * NW);
constexpr long PLSTRIDE = (long)NH * NW;   // 25600
constexpr int T5S = 392;                   // tmp5 per-field stride (+8 pad)

__global__ void __launch_bounds__(256)
cc3d_main(const float* __restrict__ in, const float* __restrict__ tg,
          const float* __restrict__ fl, float* __restrict__ out,
          double* __restrict__ acc_ws, unsigned* __restrict__ cnt_ws)
{
    __shared__ float inH[2][24 * 24];
    __shared__ float tgH[2][24 * 24];
    __shared__ float tmp5[5 * T5S];
    __shared__ float Pbuf[5 * 256];
    __shared__ float red[4];

    const int tid = threadIdx.x;
    const int w0 = blockIdx.x * TW;
    const int h0 = blockIdx.y * TH;
    const int bz = blockIdx.z;
    const int b  = bz / NDCH;
    const int d0 = (bz - b * NDCH) * DCHUNK;

    // ---- halo-load lane mapping (tid<144: row hr, 4-wide segment hq) ----
    const int hr = tid / 6, hq = tid - hr * 6;
    const int gh = h0 - 4 + hr;
    const int gw = w0 - 4 + hq * 4;     // segment entirely in or out of bounds
    const bool ld_ok = (tid < 144) &&
        ((unsigned)gh < (unsigned)NH) && ((unsigned)gw < (unsigned)NW);
    const long haloBase = (long)b * ND * PLSTRIDE + (long)gh * NW + gw;

    const int hh = tid >> 4, ww = tid & 15;
    const long flBase = (long)b * ND * PLSTRIDE + (long)(h0 + hh) * NW + (w0 + ww);

    float4 pvi, pvt;        // in-flight halo loads for the next plane

    // issue global loads for `plane` (if it exists and is in-bounds)
    auto issue = [&](int plane) {
        const int dp = d0 - 4 + plane;
        if (plane < NPLANES && ld_ok && dp >= 0 && dp < ND) {
            const float* pi = in + haloBase + (long)dp * PLSTRIDE;
            const float* pt = tg + haloBase + (long)dp * PLSTRIDE;
            pvi = *reinterpret_cast<const float4*>(pi);
            pvt = *reinterpret_cast<const float4*>(pt);
        }
    };
    // store the in-flight loads for `plane` into halo buffer plane&1
    auto store_halo = [&](int plane) {
        if (plane >= NPLANES) return;                 // block-uniform
        const int dp = d0 - 4 + plane;
        const bool v = ld_ok && (dp >= 0) && (dp < ND);
        if (tid < 144) {
            float4 wi = make_float4(0.f, 0.f, 0.f, 0.f);
            float4 wt = make_float4(0.f, 0.f, 0.f, 0.f);
            if (v) {
                wi = pvi;
                wt.x = fmaf(pvt.x, 0.5f, 0.5f);
                wt.y = fmaf(pvt.y, 0.5f, 0.5f);
                wt.z = fmaf(pvt.z, 0.5f, 0.5f);
                wt.w = fmaf(pvt.w, 0.5f, 0.5f);
            }
            reinterpret_cast<float4*>(inH[plane & 1])[tid] = wi;
            reinterpret_cast<float4*>(tgH[plane & 1])[tid] = wt;
        }
    };

    float ring[45];
    #pragma unroll
    for (int i = 0; i < 45; ++i) ring[i] = 0.f;
    float S[5] = {0.f, 0.f, 0.f, 0.f, 0.f};
    float acc = 0.f;
    float flow_pre = 0.f;

    // ---- prologue: plane 0 into H[0]; loads for plane 1 in flight ----
    issue(0);
    store_halo(0);
    issue(1);
    __syncthreads();

    for (int pbase = 0; pbase < NPLANES; pbase += 9) {
        #pragma unroll
        for (int jj = 0; jj < 9; ++jj) {
            const int p = pbase + jj;       // p % 9 == jj (static ring slot)
            if (p < NPLANES) {              // block-uniform
                const float flow_cur = flow_pre;

                store_halo(p + 1);          // consumes in-flight loads
                issue(p + 2);               // next loads into the air
                if (p >= 7 && p < NPLANES - 1)
                    flow_pre = fl[flBase + (long)(d0 + p - 7) * PLSTRIDE];

                // ---- step2: w-direction 9-sums of 5 fields -> tmp5 ----
                {
                    const float* curI = inH[p & 1];
                    const float* curT = tgH[p & 1];
                    #pragma unroll
                    for (int rep = 0; rep < 2; ++rep) {
                        const int idx = tid + rep * 256;
                        if (idx < 384) {
                            const int rr = idx >> 4, wo = idx & 15;
                            const float* ir = curI + rr * 24 + wo;
                            const float* tr = curT + rr * 24 + wo;
                            float s0 = 0.f, s1 = 0.f, s2 = 0.f, s3 = 0.f, s4 = 0.f;
                            #pragma unroll
                            for (int k = 0; k < 9; ++k) {
                                const float iv = ir[k];
                                const float t  = tr[k];   // pad cells are 0
                                s0 += t;
                                s1 += iv;
                                s2 = fmaf(t,  t,  s2);
                                s3 = fmaf(iv, iv, s3);
                                s4 = fmaf(iv, t,  s4);
                            }
                            const int o = rr * 16 + wo;
                            tmp5[0 * T5S + o] = s0;
                            tmp5[1 * T5S + o] = s1;
                            tmp5[2 * T5S + o] = s2;
                            tmp5[3 * T5S + o] = s3;
                            tmp5[4 * T5S + o] = s4;
                        }
                    }
                }
                __syncthreads();   // B: tmp5 ready

                // ---- step3: h-direction sliding 9-sums -> Pbuf ----
                if (tid < 80) {
                    const int f = tid >> 4, w = tid & 15;
                    const float* bp = tmp5 + f * T5S + w;
                    float s = 0.f;
                    #pragma unroll
                    for (int r = 0; r < 8; ++r) s += bp[r * 16];
                    #pragma unroll
                    for (int ho = 0; ho < 16; ++ho) {
                        s += bp[(ho + 8) * 16];
                        Pbuf[f * 256 + ho * 16 + w] = s;
                        s -= bp[ho * 16];
                    }
                }
                __syncthreads();   // C: Pbuf ready (also fences halo/tmp5 reuse)

                // ---- D-window ring update (slot jj is compile-time) ----
                #pragma unroll
                for (int f = 0; f < 5; ++f) {
                    const float pn = Pbuf[f * 256 + tid];
                    S[f] += pn - ring[jj * 5 + f];
                    ring[jj * 5 + f] = pn;
                }

                // ---- consume output dout = d0 + p - 8 ----
                if (p >= 8) {
                    const float wgt = 1.0f / (1.0f + __expf(-flow_cur));
                    const float Ts = S[0], Is = S[1], TTs = S[2], IIs = S[3], ITs = S[4];
                    const float Ihat = Is * INV_K;
                    const float That = Ts * INV_K;
                    const float cross = ITs - Ihat * Ts - That * Is + That * Ihat * 729.0f;
                    const float T_var = TTs - 2.0f * That * Ts + That * That * 729.0f;
                    const float I_var = IIs - 2.0f * Ihat * Is + Ihat * Ihat * 729.0f;
                    acc += cross * cross * wgt / (T_var * I_var + 1e-5f);
                }
            }
        }
    }

    // ---- block reduction -> device atomic; last block finalizes ----
    #pragma unroll
    for (int off = 32; off > 0; off >>= 1) acc += __shfl_down(acc, off);
    if ((tid & 63) == 0) red[tid >> 6] = acc;
    __syncthreads();
    if (tid == 0) {
        const double v = (double)red[0] + (double)red[1] + (double)red[2] + (double)red[3];
        atomicAdd(acc_ws, v);
        __threadfence();
        const unsigned done = atomicAdd(cnt_ws, 1u);
        if (done == (unsigned)(NBLOCKS - 1)) {
            __threadfence();
            const double a = atomicAdd(acc_ws, 0.0);   // coherent read
            out[0] = (float)(-(a * INV_COUNT));
        }
    }
}

extern "C" void kernel_launch(void* const* d_in, const int* in_sizes, int n_in,
                              void* d_out, int out_size, void* d_ws, size_t ws_size,
                              hipStream_t stream)
{
    const float* in = (const float*)d_in[0];   // 'input'
    const float* tg = (const float*)d_in[1];   // 'target'
    const float* fl = (const float*)d_in[2];   // 'flow'
    float* out = (float*)d_out;
    double* acc = (double*)d_ws;
    unsigned* cnt = (unsigned*)((char*)d_ws + 8);

    hipMemsetAsync(d_ws, 0, 16, stream);  // zero acc + counter (graph-safe)

    dim3 grid(NW / TW, NH / TH, NB * NDCH);  // (10, 10, 16) = 1600 blocks
    cc3d_main<<<grid, dim3(256), 0, stream>>>(in, tg, fl, out, acc, cnt);
}